// Round 15
// baseline (282.315 us; speedup 1.0000x reference)
//
#include <hip/hip_runtime.h>
#include <hip/hip_bf16.h>

typedef __attribute__((ext_vector_type(8))) short short8;
typedef __attribute__((ext_vector_type(4))) float f32x4;

#define N0 65536
#define N1 16384
#define N2 4096
#define N3 1024

__device__ __forceinline__ float bfu(unsigned short u) {
    unsigned int x = ((unsigned int)u) << 16;
    return __builtin_bit_cast(float, x);
}
__device__ __forceinline__ unsigned short fbf(float f) {
    return __builtin_bit_cast(unsigned short, __float2bfloat16(f));
}

// ---------------------------------------------------------------------------
// prep_all (r12-proven): Wt[k][d][c]=bf16(W[k][c][d]) for A|B|C|D (89*4096),
// Wgb[0]=bf16(Wg1), Wgb[1]=bf16(Wg0), pack0=[bB|bout|bg1], pack1=[bC|bout|bg0].
// ---------------------------------------------------------------------------
__global__ void prep_all(const float* __restrict__ A, const float* __restrict__ B,
                         const float* __restrict__ C, const float* __restrict__ D,
                         const float* __restrict__ Wg0, const float* __restrict__ Wg1,
                         const float* __restrict__ bB, const float* __restrict__ bC,
                         const float* __restrict__ bout, const float* __restrict__ bg0,
                         const float* __restrict__ bg1,
                         __hip_bfloat16* __restrict__ Wt,
                         __hip_bfloat16* __restrict__ Wgb,
                         float* __restrict__ pack)
{
    int i = blockIdx.x * 256 + threadIdx.x;
    if (i < 89 * 4096) {
        int k = i >> 12, r = i & 4095, d = r >> 6, c = r & 63;
        const float* src; int kl;
        if (k < 27)      { src = A; kl = k; }
        else if (k < 54) { src = B; kl = k - 27; }
        else if (k < 81) { src = C; kl = k - 54; }
        else             { src = D; kl = k - 81; }
        Wt[i] = __float2bfloat16(src[(kl << 12) + (c << 6) + d]);
        return;
    }
    int j = i - 89 * 4096;
    if (j < 2048) { Wgb[j] = __float2bfloat16(Wg1[j]); return; }
    j -= 2048;
    if (j < 2048) { Wgb[2048 + j] = __float2bfloat16(Wg0[j]); return; }
    j -= 2048;
    if (j < 160) {
        pack[j] = (j < 64) ? bB[j] : (j < 96) ? bout[j - 64] : bg1[j - 96];
        return;
    }
    j -= 160;
    if (j < 160) {
        pack[160 + j] = (j < 64) ? bC[j] : (j < 96) ? bout[j - 64] : bg0[j - 96];
    }
}

// ---------------------------------------------------------------------------
// spconv_direct (NEW, N0 convs only): A-operand loaded per-lane global->VGPR
// (each lane's MFMA A-fragment = 16B contiguous of its gathered row: bytes
// lh*16 and 64+lh*16 of feat[j[arow]]); B weights LDS-staged as before.
// LDS = Bbuf 16KB + ushort jl 3.4KB = 19.4KB -> 8 blocks/CU (32 waves, 2x r14)
// on the latency-bound gather loop. jl is ushort: valid ONLY for Nin<=65536.
// Counted pipeline: queue [B(k)2, A(k)2, B(k+1)2, A(k+1)2]; vmcnt(6) retires
// exactly B(k); A-reg waits are compiler-tracked (plain loads). A-regs
// double-buffered via named sets x/y in an even/odd unrolled loop (r7 shape).
// ---------------------------------------------------------------------------
__global__ __launch_bounds__(256) void spconv_direct(
    const __hip_bfloat16* __restrict__ feat, const int* __restrict__ nmap,
    const __hip_bfloat16* __restrict__ Wt, __hip_bfloat16* __restrict__ outp,
    const float* __restrict__ bias, int K, int dorelu)
{
    __shared__ short Bbuf[2][64 * 64];        // 16 KB
    __shared__ unsigned short jl[27 * 64];    // 3.4 KB

    const int t = threadIdx.x;
    const int w = t >> 6, l = t & 63;
    const int lr = l & 15, lh = l >> 4;
    const int row0 = blockIdx.x * 64;

    for (int i = t; i < K * 64; i += 256) {
        int k = i >> 6, r = i & 63;
        jl[i] = (unsigned short)nmap[(size_t)(row0 + r) * K + k];
    }
    __syncthreads();

    const int rr0 = (w << 4) + (l >> 3);
    const int qq = (l & 7) ^ (l >> 3);
    const int arow = (w << 4) + lr;

    auto stageB = [&](int buf, int k) {
        const __hip_bfloat16* Wk = Wt + (size_t)k * 4096;
#pragma unroll
        for (int i = 0; i < 2; ++i) {
            int rr = rr0 + (i << 3);
            __builtin_amdgcn_global_load_lds(
                (const __attribute__((address_space(1))) void*)(Wk + (rr << 6) + (qq << 3)),
                (__attribute__((address_space(3))) void*)&Bbuf[buf][(w << 10) + (i << 9)],
                16, 0, 0);
        }
    };

#define LOADA(k_, A0_, A1_)                                                      \
    {                                                                            \
        int j_ = (int)jl[((k_) << 6) + arow];                                    \
        const short* fr_ = (const short*)feat + ((size_t)j_ << 6) + (lh << 3);   \
        A0_ = *(const short8*)fr_;                                               \
        A1_ = *(const short8*)(fr_ + 32);                                        \
    }

#define DCOMPUTE(cur_, A0_, A1_)                                                 \
    {                                                                            \
        const short* Bb = Bbuf[cur_];                                            \
        _Pragma("unroll")                                                        \
        for (int kk = 0; kk < 2; ++kk) {                                         \
            int q = (kk << 2) + lh;                                              \
            short8 a = kk ? A1_ : A0_;                                           \
            _Pragma("unroll")                                                    \
            for (int ct = 0; ct < 4; ++ct) {                                     \
                int dr = (ct << 4) + lr;                                         \
                short8 b = *(const short8*)&Bb[(dr << 6) + ((q ^ (dr & 7)) << 3)];\
                acc[ct] = __builtin_amdgcn_mfma_f32_16x16x32_bf16(a, b, acc[ct], 0, 0, 0); \
            }                                                                    \
        }                                                                        \
    }

    f32x4 acc[4] = {};
    short8 a0x, a1x, a0y, a1y;

    stageB(0, 0);          // oldest-first: B(0) before A(0) so vmcnt(6) retires B
    LOADA(0, a0x, a1x)

    int cur = 0;
    for (int k = 0; k < K; k += 2) {
        if (k + 1 < K) {
            stageB(cur ^ 1, k + 1);
            LOADA(k + 1, a0y, a1y)
            asm volatile("s_waitcnt vmcnt(6)" ::: "memory");   // retire B(k) only
        } else {
            asm volatile("s_waitcnt vmcnt(0)" ::: "memory");
        }
        asm volatile("s_barrier" ::: "memory");
        DCOMPUTE(cur, a0x, a1x)
        asm volatile("s_barrier" ::: "memory");
        cur ^= 1;
        if (k + 1 < K) {
            if (k + 2 < K) {
                stageB(cur ^ 1, k + 2);
                LOADA(k + 2, a0x, a1x)
                asm volatile("s_waitcnt vmcnt(6)" ::: "memory");
            } else {
                asm volatile("s_waitcnt vmcnt(0)" ::: "memory");
            }
            asm volatile("s_barrier" ::: "memory");
            DCOMPUTE(cur, a0y, a1y)
            asm volatile("s_barrier" ::: "memory");
            cur ^= 1;
        }
    }
#undef LOADA
#undef DCOMPUTE

#pragma unroll
    for (int ct = 0; ct < 4; ++ct) {
        int col = (ct << 4) + lr;
        float bv = dorelu ? bias[col] : 0.f;
#pragma unroll
        for (int rr = 0; rr < 4; ++rr) {
            int row = row0 + (w << 4) + (lh << 2) + rr;
            float v = acc[ct][rr];
            if (dorelu) v = fmaxf(v + bv, 0.f);
            outp[((size_t)row << 6) + col] = __float2bfloat16(v);
        }
    }
}

// ---------------------------------------------------------------------------
// spconv_mfma (r10-proven verbatim, small scales): 64-row geometry, counted
// vmcnt pipeline. mode 0: bf16 raw; mode 2: bf16 bias+relu;
// mode 1: f32 partial to chunk buffer blockIdx.y (no atomics/memset).
// ---------------------------------------------------------------------------
__global__ __launch_bounds__(256) void spconv_mfma(
    const __hip_bfloat16* __restrict__ feat, const int* __restrict__ nmap,
    const __hip_bfloat16* __restrict__ Wt, void* __restrict__ outp,
    const float* __restrict__ bias, int Nout, int K, int mode)
{
    __shared__ short Abuf[2][64 * 64];
    __shared__ short Bbuf[2][64 * 64];
    __shared__ int jl[27 * 64];

    const int t = threadIdx.x;
    const int w = t >> 6, l = t & 63;
    const int lr = l & 15, lh = l >> 4;
    const int row0 = blockIdx.x * 64;
    const int per = (K + gridDim.y - 1) / gridDim.y;
    const int kb0 = blockIdx.y * per;
    const int nk = min(K, kb0 + per) - kb0;

    for (int i = t; i < nk * 64; i += 256) {
        int k = i >> 6, r = i & 63;
        jl[i] = nmap[(size_t)(row0 + r) * K + (kb0 + k)];
    }
    __syncthreads();

    const int rr0 = (w << 4) + (l >> 3);
    const int qq = (l & 7) ^ (l >> 3);

    auto stage = [&](int buf, int k) {
        const __hip_bfloat16* Wk = Wt + (size_t)(kb0 + k) * 4096;
#pragma unroll
        for (int i = 0; i < 2; ++i) {
            int rr = rr0 + (i << 3);
            int j = jl[(k << 6) + rr];
            __builtin_amdgcn_global_load_lds(
                (const __attribute__((address_space(1))) void*)(feat + ((size_t)j << 6) + (qq << 3)),
                (__attribute__((address_space(3))) void*)&Abuf[buf][(w << 10) + (i << 9)],
                16, 0, 0);
            __builtin_amdgcn_global_load_lds(
                (const __attribute__((address_space(1))) void*)(Wk + (rr << 6) + (qq << 3)),
                (__attribute__((address_space(3))) void*)&Bbuf[buf][(w << 10) + (i << 9)],
                16, 0, 0);
        }
    };

    f32x4 acc[4] = {};
    const int arow = (w << 4) + lr;

#define COMPUTE(cur_)                                                            \
    {                                                                            \
        const short* Ab = Abuf[cur_];                                            \
        const short* Bb = Bbuf[cur_];                                            \
        _Pragma("unroll")                                                        \
        for (int kk = 0; kk < 2; ++kk) {                                         \
            int q = (kk << 2) + lh;                                              \
            short8 a = *(const short8*)&Ab[(arow << 6) + ((q ^ (arow & 7)) << 3)];\
            _Pragma("unroll")                                                    \
            for (int ct = 0; ct < 4; ++ct) {                                     \
                int dr = (ct << 4) + lr;                                         \
                short8 b = *(const short8*)&Bb[(dr << 6) + ((q ^ (dr & 7)) << 3)];\
                acc[ct] = __builtin_amdgcn_mfma_f32_16x16x32_bf16(a, b, acc[ct], 0, 0, 0); \
            }                                                                    \
        }                                                                        \
    }

    stage(0, 0);

    int cur = 0;
    for (int k = 0; k < nk; ++k) {
        if (k + 1 < nk) {
            stage(cur ^ 1, k + 1);
            asm volatile("s_waitcnt vmcnt(4)" ::: "memory");
        } else {
            asm volatile("s_waitcnt vmcnt(0)" ::: "memory");
        }
        asm volatile("s_barrier" ::: "memory");
        COMPUTE(cur)
        asm volatile("s_barrier" ::: "memory");
        cur ^= 1;
    }
#undef COMPUTE

    if (mode == 1) {
        float* o32 = (float*)outp + (size_t)blockIdx.y * ((size_t)Nout << 6);
#pragma unroll
        for (int ct = 0; ct < 4; ++ct) {
            int col = (ct << 4) + lr;
#pragma unroll
            for (int rr = 0; rr < 4; ++rr) {
                int row = row0 + (w << 4) + (lh << 2) + rr;
                o32[((size_t)row << 6) + col] = acc[ct][rr];
            }
        }
    } else {
        __hip_bfloat16* ob = (__hip_bfloat16*)outp;
#pragma unroll
        for (int ct = 0; ct < 4; ++ct) {
            int col = (ct << 4) + lr;
            float bv = (mode == 2) ? bias[col] : 0.f;
#pragma unroll
            for (int rr = 0; rr < 4; ++rr) {
                int row = row0 + (w << 4) + (lh << 2) + rr;
                float v = acc[ct][rr];
                if (mode == 2) v = fmaxf(v + bv, 0.f);
                ob[((size_t)row << 6) + col] = __float2bfloat16(v);
            }
        }
    }
}

// ---------------------------------------------------------------------------
// spconv_fused (r12/r14-proven): conv + {t=relu(acc+bconv); hx -> hx_out;
// g=sigmoid(hx@Wg+bg); gout=bf16(g*t)}. B/C convs at N<=16384 only.
// ---------------------------------------------------------------------------
__global__ __launch_bounds__(256) void spconv_fused(
    const __hip_bfloat16* __restrict__ feat, const int* __restrict__ nmap,
    const __hip_bfloat16* __restrict__ Wt, int K,
    const float* __restrict__ Woutg, const __hip_bfloat16* __restrict__ Wgb,
    const float* __restrict__ pack, float* __restrict__ hx_out,
    __hip_bfloat16* __restrict__ gout)
{
    __shared__ int ldsm[10240];
    short* AbufS = (short*)ldsm;
    short* BbufS = (short*)(ldsm + 4096);
    int*   jl    = ldsm + 8192;
    short* WgL   = (short*)(ldsm + 8192);
    float* packL = (float*)(ldsm + 8192 + 1024);

    const int t = threadIdx.x;
    const int w = t >> 6, l = t & 63;
    const int lr = l & 15, lh = l >> 4;
    const int row0 = blockIdx.x * 64;

    for (int i = t; i < K * 64; i += 256) {
        int k = i >> 6, r = i & 63;
        jl[i] = nmap[(size_t)(row0 + r) * K + k];
    }
    __syncthreads();

    const int rr0 = (w << 4) + (l >> 3);
    const int qq = (l & 7) ^ (l >> 3);

    auto stage = [&](int buf, int k) {
        const __hip_bfloat16* Wk = Wt + (size_t)k * 4096;
#pragma unroll
        for (int i = 0; i < 2; ++i) {
            int rr = rr0 + (i << 3);
            int j = jl[(k << 6) + rr];
            __builtin_amdgcn_global_load_lds(
                (const __attribute__((address_space(1))) void*)(feat + ((size_t)j << 6) + (qq << 3)),
                (__attribute__((address_space(3))) void*)(AbufS + buf * 4096 + (w << 10) + (i << 9)),
                16, 0, 0);
            __builtin_amdgcn_global_load_lds(
                (const __attribute__((address_space(1))) void*)(Wk + (rr << 6) + (qq << 3)),
                (__attribute__((address_space(3))) void*)(BbufS + buf * 4096 + (w << 10) + (i << 9)),
                16, 0, 0);
        }
    };

    auto stage_epi = [&](int buf) {
        short* dstW = BbufS + buf * 4096;
#pragma unroll
        for (int i = 0; i < 2; ++i) {
            int s = t + i * 256;
            int r = s >> 3, qp = s & 7;
            int q = qp ^ (r >> 4);
            __builtin_amdgcn_global_load_lds(
                (const __attribute__((address_space(1))) void*)(Woutg + (r << 5) + (q << 2)),
                (__attribute__((address_space(3))) void*)(dstW + (w << 9) + (i << 11)),
                16, 0, 0);
        }
        __builtin_amdgcn_global_load_lds(
            (const __attribute__((address_space(1))) void*)(Wgb + (t << 3)),
            (__attribute__((address_space(3))) void*)(WgL + (w << 9)),
            16, 0, 0);
        if (t < 40)
            __builtin_amdgcn_global_load_lds(
                (const __attribute__((address_space(1))) void*)(pack + (t << 2)),
                (__attribute__((address_space(3))) void*)packL,
                16, 0, 0);
    };

    f32x4 acc[4] = {};
    const int arow = (w << 4) + lr;

#define COMPUTE(cur_)                                                            \
    {                                                                            \
        const short* Ab = AbufS + (cur_) * 4096;                                 \
        const short* Bb = BbufS + (cur_) * 4096;                                 \
        _Pragma("unroll")                                                        \
        for (int kk = 0; kk < 2; ++kk) {                                         \
            int q = (kk << 2) + lh;                                              \
            short8 a = *(const short8*)&Ab[(arow << 6) + ((q ^ (arow & 7)) << 3)];\
            _Pragma("unroll")                                                    \
            for (int ct = 0; ct < 4; ++ct) {                                     \
                int dr = (ct << 4) + lr;                                         \
                short8 b = *(const short8*)&Bb[(dr << 6) + ((q ^ (dr & 7)) << 3)];\
                acc[ct] = __builtin_amdgcn_mfma_f32_16x16x32_bf16(a, b, acc[ct], 0, 0, 0); \
            }                                                                    \
        }                                                                        \
    }

    stage(0, 0);

    int cur = 0;
    for (int k = 0; k < K; ++k) {
        if (k + 1 < K) {
            stage(cur ^ 1, k + 1);
            asm volatile("s_waitcnt vmcnt(4)" ::: "memory");
        } else {
            stage_epi(cur ^ 1);
            asm volatile("s_waitcnt vmcnt(0)" ::: "memory");
        }
        asm volatile("s_barrier" ::: "memory");
        COMPUTE(cur)
        asm volatile("s_barrier" ::: "memory");
        cur ^= 1;
    }
#undef COMPUTE
    // epi weights now in BbufS[cur], WgL, packL

    short* tl = AbufS;                       // t-tile [64][72] bf16 (Abuf dead)
    float* WoutL = (float*)(BbufS + cur * 4096);

#pragma unroll
    for (int ct = 0; ct < 4; ++ct) {
        int col = (ct << 4) + lr;
        float bv = packL[col];
#pragma unroll
        for (int rr = 0; rr < 4; ++rr) {
            int rl = (w << 4) + (lh << 2) + rr;
            float v = fmaxf(acc[ct][rr] + bv, 0.f);
            tl[rl * 72 + col] = (short)fbf(v);
        }
    }
    __syncthreads();

    const int g4 = t & 3, rloc = t >> 2;
    const short* trow = tl + rloc * 72 + (g4 << 4);
    float tv[16];
    {
        short8 u0 = *(const short8*)trow;
        short8 u1 = *(const short8*)(trow + 8);
#pragma unroll
        for (int j = 0; j < 8; ++j) {
            tv[j]     = bfu((unsigned short)u0[j]);
            tv[8 + j] = bfu((unsigned short)u1[j]);
        }
    }
    float ph[32];
#pragma unroll
    for (int d = 0; d < 32; ++d) ph[d] = 0.f;
#pragma unroll
    for (int i = 0; i < 16; ++i) {
        float tc = tv[i];
        const float* wrow = WoutL + (((g4 << 4) + i) << 5);
#pragma unroll
        for (int q = 0; q < 8; ++q) {
            f32x4 wv = *(const f32x4*)&wrow[(q ^ g4) << 2];
            ph[q * 4 + 0] = fmaf(tc, wv[0], ph[q * 4 + 0]);
            ph[q * 4 + 1] = fmaf(tc, wv[1], ph[q * 4 + 1]);
            ph[q * 4 + 2] = fmaf(tc, wv[2], ph[q * 4 + 2]);
            ph[q * 4 + 3] = fmaf(tc, wv[3], ph[q * 4 + 3]);
        }
    }
#pragma unroll
    for (int m = 1; m < 4; m <<= 1) {
#pragma unroll
        for (int d = 0; d < 32; ++d) ph[d] += __shfl_xor(ph[d], m);
    }
#pragma unroll
    for (int d = 0; d < 32; ++d) ph[d] += packL[64 + d];

    {
        float* ho = hx_out + ((size_t)(row0 + rloc) << 5);
#pragma unroll
        for (int G = 0; G < 4; ++G)
            if (g4 == G) {
                float4 v0 = {ph[G * 8 + 0], ph[G * 8 + 1], ph[G * 8 + 2], ph[G * 8 + 3]};
                float4 v1 = {ph[G * 8 + 4], ph[G * 8 + 5], ph[G * 8 + 6], ph[G * 8 + 7]};
                ((float4*)ho)[G * 2 + 0] = v0;
                ((float4*)ho)[G * 2 + 1] = v1;
            }
    }

    float ga[16];
#pragma unroll
    for (int j = 0; j < 16; ++j) ga[j] = packL[96 + (g4 << 4) + j];
#pragma unroll
    for (int d = 0; d < 32; ++d) {
        float hd = ph[d];
        const short* wg = WgL + (d << 6) + (g4 << 4);
        short8 w0 = *(const short8*)wg;
        short8 w1 = *(const short8*)(wg + 8);
#pragma unroll
        for (int j = 0; j < 8; ++j) {
            ga[j]     = fmaf(hd, bfu((unsigned short)w0[j]), ga[j]);
            ga[8 + j] = fmaf(hd, bfu((unsigned short)w1[j]), ga[8 + j]);
        }
    }
    {
        short8 o0, o1;
#pragma unroll
        for (int j = 0; j < 8; ++j) {
            float g0 = 1.f / (1.f + __expf(-ga[j]));
            float g1 = 1.f / (1.f + __expf(-ga[8 + j]));
            o0[j] = (short)fbf(g0 * tv[j]);
            o1[j] = (short)fbf(g1 * tv[8 + j]);
        }
        short* go = (short*)gout + ((size_t)(row0 + rloc) << 6) + (g4 << 4);
        *(short8*)go = o0;
        *(short8*)(go + 8) = o1;
    }
}

// ---------------------------------------------------------------------------
// reduce_relu_bf (r10-proven): out_bf16 = relu(sum_ch chunk + bias[c])
// ---------------------------------------------------------------------------
__global__ void reduce_relu_bf(const float* __restrict__ in, const float* __restrict__ bias,
                               __hip_bfloat16* __restrict__ outb, int nv, int ch)
{
    int i = blockIdx.x * blockDim.x + threadIdx.x;
    if (i >= nv) return;
    const float4* in4 = (const float4*)in;
    float4 s = in4[i];
    for (int c = 1; c < ch; ++c) {
        float4 v = in4[(size_t)c * nv + i];
        s.x += v.x; s.y += v.y; s.z += v.z; s.w += v.w;
    }
    int cb = (i << 2) & 63;
    ushort4 o;
    o.x = fbf(fmaxf(s.x + bias[cb + 0], 0.f));
    o.y = fbf(fmaxf(s.y + bias[cb + 1], 0.f));
    o.z = fbf(fmaxf(s.z + bias[cb + 2], 0.f));
    o.w = fbf(fmaxf(s.w + bias[cb + 3], 0.f));
    ((ushort4*)outb)[i] = o;
}

// ---------------------------------------------------------------------------
// epi_full (r10-proven, 8 lanes/row). smode 0: bf16 +bias+relu; 2: f32 raw.
// ---------------------------------------------------------------------------
__global__ __launch_bounds__(256) void epi_full(
    const void* __restrict__ srcp, int smode, int ch, const float* __restrict__ bconv,
    const float* __restrict__ Wout, const float* __restrict__ bout,
    const float* __restrict__ Wg, const float* __restrict__ bg,
    float* __restrict__ hx_out, __hip_bfloat16* __restrict__ gout, int N)
{
    __shared__ float Woutl[64 * 32];
    __shared__ float Wgl[32 * 64];
    __shared__ float boutl[32];
    __shared__ float bgl[64];
    __shared__ float bcl[64];

    const int t = threadIdx.x;
    for (int i = t; i < 2048; i += 256) {
        int r = i >> 5, col = i & 31;
        int q = col >> 2, e = col & 3;
        Woutl[(r << 5) + ((q ^ (r >> 3)) << 2) + e] = Wout[i];
        Wgl[i] = Wg[i];
    }
    if (t < 32) boutl[t] = bout[t];
    if (t >= 64 && t < 128) bgl[t - 64] = bg[t - 64];
    if (t >= 128 && t < 192) bcl[t - 128] = bconv ? bconv[t - 128] : 0.f;
    __syncthreads();

    const int g = t & 7;
    const int row = blockIdx.x * 32 + (t >> 3);
    const int c0 = g << 3;

    float tv[8];
    if (smode == 0) {
        const ushort4* sb = (const ushort4*)((const __hip_bfloat16*)srcp + ((size_t)row << 6) + c0);
        ushort4 v0 = sb[0], v1 = sb[1];
        tv[0] = bfu(v0.x); tv[1] = bfu(v0.y); tv[2] = bfu(v0.z); tv[3] = bfu(v0.w);
        tv[4] = bfu(v1.x); tv[5] = bfu(v1.y); tv[6] = bfu(v1.z); tv[7] = bfu(v1.w);
    } else {
        const float4* sf = (const float4*)((const float*)srcp + ((size_t)row << 6) + c0);
        float4 a = sf[0], b = sf[1];
        tv[0] = a.x; tv[1] = a.y; tv[2] = a.z; tv[3] = a.w;
        tv[4] = b.x; tv[5] = b.y; tv[6] = b.z; tv[7] = b.w;
    }
    if (smode != 2) {
#pragma unroll
        for (int i = 0; i < 8; ++i) tv[i] = fmaxf(tv[i] + bcl[c0 + i], 0.f);
    }

    float ph[32];
#pragma unroll
    for (int d = 0; d < 32; ++d) ph[d] = 0.f;
#pragma unroll
    for (int i = 0; i < 8; ++i) {
        float tc = tv[i];
        const float* wr = &Woutl[(c0 + i) << 5];
#pragma unroll
        for (int q = 0; q < 8; ++q) {
            f32x4 wv = *(const f32x4*)&wr[(q ^ g) << 2];
            ph[q * 4 + 0] = fmaf(tc, wv[0], ph[q * 4 + 0]);
            ph[q * 4 + 1] = fmaf(tc, wv[1], ph[q * 4 + 1]);
            ph[q * 4 + 2] = fmaf(tc, wv[2], ph[q * 4 + 2]);
            ph[q * 4 + 3] = fmaf(tc, wv[3], ph[q * 4 + 3]);
        }
    }
#pragma unroll
    for (int m = 1; m < 8; m <<= 1) {
#pragma unroll
        for (int d = 0; d < 32; ++d) ph[d] += __shfl_xor(ph[d], m);
    }
#pragma unroll
    for (int d = 0; d < 32; ++d) ph[d] += boutl[d];

    {
        float* ho = hx_out + ((size_t)row << 5);
#pragma unroll
        for (int G = 0; G < 8; ++G)
            if (g == G) {
                float4 v = {ph[G * 4 + 0], ph[G * 4 + 1], ph[G * 4 + 2], ph[G * 4 + 3]};
                ((float4*)ho)[G] = v;
            }
    }

    float ga[8];
#pragma unroll
    for (int j = 0; j < 8; ++j) ga[j] = bgl[c0 + j];
#pragma unroll
    for (int d = 0; d < 32; ++d) {
        float hd = ph[d];
        const float* wr = &Wgl[(d << 6) + c0];
        f32x4 w0 = *(const f32x4*)&wr[0];
        f32x4 w1 = *(const f32x4*)&wr[4];
        ga[0] = fmaf(hd, w0[0], ga[0]); ga[1] = fmaf(hd, w0[1], ga[1]);
        ga[2] = fmaf(hd, w0[2], ga[2]); ga[3] = fmaf(hd, w0[3], ga[3]);
        ga[4] = fmaf(hd, w1[0], ga[4]); ga[5] = fmaf(hd, w1[1], ga[5]);
        ga[6] = fmaf(hd, w1[2], ga[6]); ga[7] = fmaf(hd, w1[3], ga[7]);
    }
    {
        unsigned short ob[8];
#pragma unroll
        for (int j = 0; j < 8; ++j) {
            float gg = 1.f / (1.f + __expf(-ga[j]));
            ob[j] = fbf(gg * tv[j]);
        }
        ushort4* go = (ushort4*)(gout + ((size_t)row << 6) + c0);
        ushort4 o0 = {ob[0], ob[1], ob[2], ob[3]};
        ushort4 o1 = {ob[4], ob[5], ob[6], ob[7]};
        go[0] = o0; go[1] = o1;
    }
}

// ---------------------------------------------------------------------------
extern "C" void kernel_launch(void* const* d_in, const int* in_sizes, int n_in,
                              void* d_out, int out_size, void* d_ws, size_t ws_size,
                              hipStream_t stream)
{
    const float* x    = (const float*)d_in[0];
    const float* Wg0  = (const float*)d_in[1];
    const float* bg0  = (const float*)d_in[2];
    const float* Wg1  = (const float*)d_in[3];
    const float* bg1  = (const float*)d_in[4];
    const float* Wout = (const float*)d_in[5];
    const float* bout = (const float*)d_in[6];
    const float* WA   = (const float*)d_in[7];
    const float* bA   = (const float*)d_in[8];
    const float* WB   = (const float*)d_in[9];
    const float* bB   = (const float*)d_in[10];
    const float* WD   = (const float*)d_in[11];
    const float* bD   = (const float*)d_in[12];
    const float* WC   = (const float*)d_in[13];
    const float* bC   = (const float*)d_in[14];
    const int* nmap[4] = {(const int*)d_in[15], (const int*)d_in[16],
                          (const int*)d_in[17], (const int*)d_in[18]};
    const int* ndm[3]  = {(const int*)d_in[19], (const int*)d_in[20],
                          (const int*)d_in[21]};

    float* out = (float*)d_out;
    __hip_bfloat16* featbf0 = (__hip_bfloat16*)d_ws;
    __hip_bfloat16* featbf1 = featbf0 + (size_t)N0 * 64;
    __hip_bfloat16* convbf  = featbf1 + (size_t)N0 * 64;
    float* conv32 = (float*)(convbf + (size_t)N0 * 64);   // up to 8 chunks of N2*64 f32
    __hip_bfloat16* WAt = (__hip_bfloat16*)(conv32 + (size_t)N2 * 64 * 8);
    __hip_bfloat16* WBt = WAt + 27 * 4096;
    __hip_bfloat16* WCt = WBt + 27 * 4096;
    __hip_bfloat16* WDt = WCt + 27 * 4096;
    __hip_bfloat16* Wgb = WDt + 8 * 4096;         // [0]=bf16(Wg1), [1]=bf16(Wg0)
    float* packw = (float*)(Wgb + 4096);          // pack0 (160) | pack1 (160)

    const int Ns[4] = {N0, N1, N2, N3};
    size_t off[7];
    off[0] = 0;
    off[1] = off[0] + (size_t)N0 * 32;
    off[2] = off[1] + (size_t)N0 * 32;
    off[3] = off[2] + (size_t)N1 * 32;
    off[4] = off[3] + (size_t)N1 * 32;
    off[5] = off[4] + (size_t)N2 * 32;
    off[6] = off[5] + (size_t)N2 * 32;

    hipLaunchKernelGGL(prep_all, dim3((89 * 4096 + 4416 + 255) / 256), dim3(256), 0, stream,
                       WA, WB, WC, WD, Wg0, Wg1, bB, bC, bout, bg0, bg1,
                       WAt, Wgb, packw);

    // r10 chunk policy for plain convs at small scales
    auto chunks = [&](int Nout, int K) -> int {
        if (Nout >= 16384) return 1;
        if (Nout == 4096) return (K == 27) ? 4 : 2;
        return (K == 27) ? 7 : 4;   // N3
    };
    // plain conv (A/D): returns ch if f32 chunk partials in conv32, else 0
    auto convAD = [&](const __hip_bfloat16* fin, const int* nm,
                      const __hip_bfloat16* Wt, int Nout, int K,
                      const float* bias2, __hip_bfloat16* dst) -> int {
        int ch = chunks(Nout, K);
        if (ch > 1) {
            hipLaunchKernelGGL(spconv_mfma, dim3(Nout / 64, ch), dim3(256), 0, stream,
                               fin, nm, Wt, (void*)conv32, (const float*)nullptr,
                               Nout, K, 1);
            return ch;
        }
        hipLaunchKernelGGL(spconv_mfma, dim3(Nout / 64, 1), dim3(256), 0, stream,
                           fin, nm, Wt, (void*)dst, bias2, Nout, K, 2);
        return 0;
    };

    // init: hx0 -> out0 ; featbf0 = bf16(sigmoid(hx0@Wg0+bg0) * x)
    hipLaunchKernelGGL(epi_full, dim3(N0 / 32), dim3(256), 0, stream,
                       (const void*)x, 2, 1, (const float*)nullptr, Wout, bout, Wg0, bg0,
                       out + off[0], featbf0, N0);

    for (int s = 0; s < 3; ++s) {
        int N = Ns[s], Nn = Ns[s + 1];

        // ---- conv A (bias+relu) -> featbf1 ----
        if (N >= 65536) {
            // N0: A-direct-to-register kernel (8 blocks/CU)
            hipLaunchKernelGGL(spconv_direct, dim3(N / 64), dim3(256), 0, stream,
                               featbf0, nmap[s], WAt, featbf1, bA, 27, 1);
        } else {
            int mA = convAD(featbf0, nmap[s], WAt, N, 27, bA, featbf1);
            if (mA)
                hipLaunchKernelGGL(reduce_relu_bf, dim3((N * 16 + 255) / 256), dim3(256), 0, stream,
                                   conv32, bA, featbf1, N * 16, mA);
        }

        // ---- conv B: direct+epi at N0, fused at N<=16384 ----
        if (N >= 65536) {
            hipLaunchKernelGGL(spconv_direct, dim3(N / 64), dim3(256), 0, stream,
                               featbf1, nmap[s], WBt, convbf, (const float*)nullptr, 27, 0);
            hipLaunchKernelGGL(epi_full, dim3(N / 32), dim3(256), 0, stream,
                               (const void*)convbf, 0, 1, bB, Wout, bout, Wg1, bg1,
                               out + off[s * 2 + 1], featbf0, N);
        } else {
            hipLaunchKernelGGL(spconv_fused, dim3(N / 64), dim3(256), 0, stream,
                               featbf1, nmap[s], WBt, 27,
                               Wout, Wgb, packw, out + off[s * 2 + 1], featbf0);
        }

        // ---- conv D (downsample, bias+relu) -> featbf1 ----
        int mD = convAD(featbf0, ndm[s], WDt, Nn, 8, bD, featbf1);
        if (mD)
            hipLaunchKernelGGL(reduce_relu_bf, dim3((Nn * 16 + 255) / 256), dim3(256), 0, stream,
                               conv32, bD, featbf1, Nn * 16, mD);

        // ---- conv C: always N<=16384 -> fused ----
        hipLaunchKernelGGL(spconv_fused, dim3(Nn / 64), dim3(256), 0, stream,
                           featbf1, nmap[s + 1], WCt, 27,
                           Wout, Wgb + 2048, packw + 160, out + off[s * 2 + 2], featbf0);
    }
}

// Round 16
// 264.080 us; speedup vs baseline: 1.0690x; 1.0690x over previous
//
#include <hip/hip_runtime.h>
#include <hip/hip_bf16.h>

typedef __attribute__((ext_vector_type(8))) short short8;
typedef __attribute__((ext_vector_type(4))) float f32x4;

#define N0 65536
#define N1 16384
#define N2 4096
#define N3 1024

__device__ __forceinline__ float bfu(unsigned short u) {
    unsigned int x = ((unsigned int)u) << 16;
    return __builtin_bit_cast(float, x);
}
__device__ __forceinline__ unsigned short fbf(float f) {
    return __builtin_bit_cast(unsigned short, __float2bfloat16(f));
}

// ---------------------------------------------------------------------------
// prep_all (r12-proven): Wt[k][d][c]=bf16(W[k][c][d]) for A|B|C|D (89*4096),
// Wgb[0]=bf16(Wg1), Wgb[1]=bf16(Wg0), pack0=[bB|bout|bg1], pack1=[bC|bout|bg0].
// ---------------------------------------------------------------------------
__global__ void prep_all(const float* __restrict__ A, const float* __restrict__ B,
                         const float* __restrict__ C, const float* __restrict__ D,
                         const float* __restrict__ Wg0, const float* __restrict__ Wg1,
                         const float* __restrict__ bB, const float* __restrict__ bC,
                         const float* __restrict__ bout, const float* __restrict__ bg0,
                         const float* __restrict__ bg1,
                         __hip_bfloat16* __restrict__ Wt,
                         __hip_bfloat16* __restrict__ Wgb,
                         float* __restrict__ pack)
{
    int i = blockIdx.x * 256 + threadIdx.x;
    if (i < 89 * 4096) {
        int k = i >> 12, r = i & 4095, d = r >> 6, c = r & 63;
        const float* src; int kl;
        if (k < 27)      { src = A; kl = k; }
        else if (k < 54) { src = B; kl = k - 27; }
        else if (k < 81) { src = C; kl = k - 54; }
        else             { src = D; kl = k - 81; }
        Wt[i] = __float2bfloat16(src[(kl << 12) + (c << 6) + d]);
        return;
    }
    int j = i - 89 * 4096;
    if (j < 2048) { Wgb[j] = __float2bfloat16(Wg1[j]); return; }
    j -= 2048;
    if (j < 2048) { Wgb[2048 + j] = __float2bfloat16(Wg0[j]); return; }
    j -= 2048;
    if (j < 160) {
        pack[j] = (j < 64) ? bB[j] : (j < 96) ? bout[j - 64] : bg1[j - 96];
        return;
    }
    j -= 160;
    if (j < 160) {
        pack[160 + j] = (j < 64) ? bC[j] : (j < 96) ? bout[j - 64] : bg0[j - 96];
    }
}

// ---------------------------------------------------------------------------
// spconv_mfma (r10-proven verbatim): 64-row geometry, counted vmcnt pipeline.
// mode 0: bf16 raw; mode 2: bf16 bias+relu;
// mode 1: f32 partial to chunk buffer blockIdx.y (no atomics/memset).
// ---------------------------------------------------------------------------
__global__ __launch_bounds__(256) void spconv_mfma(
    const __hip_bfloat16* __restrict__ feat, const int* __restrict__ nmap,
    const __hip_bfloat16* __restrict__ Wt, void* __restrict__ outp,
    const float* __restrict__ bias, int Nout, int K, int mode)
{
    __shared__ short Abuf[2][64 * 64];
    __shared__ short Bbuf[2][64 * 64];
    __shared__ int jl[27 * 64];

    const int t = threadIdx.x;
    const int w = t >> 6, l = t & 63;
    const int lr = l & 15, lh = l >> 4;
    const int row0 = blockIdx.x * 64;
    const int per = (K + gridDim.y - 1) / gridDim.y;
    const int kb0 = blockIdx.y * per;
    const int nk = min(K, kb0 + per) - kb0;

    for (int i = t; i < nk * 64; i += 256) {
        int k = i >> 6, r = i & 63;
        jl[i] = nmap[(size_t)(row0 + r) * K + (kb0 + k)];
    }
    __syncthreads();

    const int rr0 = (w << 4) + (l >> 3);
    const int qq = (l & 7) ^ (l >> 3);

    auto stage = [&](int buf, int k) {
        const __hip_bfloat16* Wk = Wt + (size_t)(kb0 + k) * 4096;
#pragma unroll
        for (int i = 0; i < 2; ++i) {
            int rr = rr0 + (i << 3);
            int j = jl[(k << 6) + rr];
            __builtin_amdgcn_global_load_lds(
                (const __attribute__((address_space(1))) void*)(feat + ((size_t)j << 6) + (qq << 3)),
                (__attribute__((address_space(3))) void*)&Abuf[buf][(w << 10) + (i << 9)],
                16, 0, 0);
            __builtin_amdgcn_global_load_lds(
                (const __attribute__((address_space(1))) void*)(Wk + (rr << 6) + (qq << 3)),
                (__attribute__((address_space(3))) void*)&Bbuf[buf][(w << 10) + (i << 9)],
                16, 0, 0);
        }
    };

    f32x4 acc[4] = {};
    const int arow = (w << 4) + lr;

#define COMPUTE(cur_)                                                            \
    {                                                                            \
        const short* Ab = Abuf[cur_];                                            \
        const short* Bb = Bbuf[cur_];                                            \
        _Pragma("unroll")                                                        \
        for (int kk = 0; kk < 2; ++kk) {                                         \
            int q = (kk << 2) + lh;                                              \
            short8 a = *(const short8*)&Ab[(arow << 6) + ((q ^ (arow & 7)) << 3)];\
            _Pragma("unroll")                                                    \
            for (int ct = 0; ct < 4; ++ct) {                                     \
                int dr = (ct << 4) + lr;                                         \
                short8 b = *(const short8*)&Bb[(dr << 6) + ((q ^ (dr & 7)) << 3)];\
                acc[ct] = __builtin_amdgcn_mfma_f32_16x16x32_bf16(a, b, acc[ct], 0, 0, 0); \
            }                                                                    \
        }                                                                        \
    }

    stage(0, 0);

    int cur = 0;
    for (int k = 0; k < nk; ++k) {
        if (k + 1 < nk) {
            stage(cur ^ 1, k + 1);
            asm volatile("s_waitcnt vmcnt(4)" ::: "memory");
        } else {
            asm volatile("s_waitcnt vmcnt(0)" ::: "memory");
        }
        asm volatile("s_barrier" ::: "memory");
        COMPUTE(cur)
        asm volatile("s_barrier" ::: "memory");
        cur ^= 1;
    }
#undef COMPUTE

    if (mode == 1) {
        float* o32 = (float*)outp + (size_t)blockIdx.y * ((size_t)Nout << 6);
#pragma unroll
        for (int ct = 0; ct < 4; ++ct) {
            int col = (ct << 4) + lr;
#pragma unroll
            for (int rr = 0; rr < 4; ++rr) {
                int row = row0 + (w << 4) + (lh << 2) + rr;
                o32[((size_t)row << 6) + col] = acc[ct][rr];
            }
        }
    } else {
        __hip_bfloat16* ob = (__hip_bfloat16*)outp;
#pragma unroll
        for (int ct = 0; ct < 4; ++ct) {
            int col = (ct << 4) + lr;
            float bv = (mode == 2) ? bias[col] : 0.f;
#pragma unroll
            for (int rr = 0; rr < 4; ++rr) {
                int row = row0 + (w << 4) + (lh << 2) + rr;
                float v = acc[ct][rr];
                if (mode == 2) v = fmaxf(v + bv, 0.f);
                ob[((size_t)row << 6) + col] = __float2bfloat16(v);
            }
        }
    }
}

// ---------------------------------------------------------------------------
// spconv_fused (r12/r14-proven): conv + {t=relu(acc+bconv); hx -> hx_out;
// g=sigmoid(hx@Wg+bg); gout=bf16(g*t)}. B/C convs at N<=16384 only.
// ---------------------------------------------------------------------------
__global__ __launch_bounds__(256) void spconv_fused(
    const __hip_bfloat16* __restrict__ feat, const int* __restrict__ nmap,
    const __hip_bfloat16* __restrict__ Wt, int K,
    const float* __restrict__ Woutg, const __hip_bfloat16* __restrict__ Wgb,
    const float* __restrict__ pack, float* __restrict__ hx_out,
    __hip_bfloat16* __restrict__ gout)
{
    __shared__ int ldsm[10240];
    short* AbufS = (short*)ldsm;
    short* BbufS = (short*)(ldsm + 4096);
    int*   jl    = ldsm + 8192;
    short* WgL   = (short*)(ldsm + 8192);
    float* packL = (float*)(ldsm + 8192 + 1024);

    const int t = threadIdx.x;
    const int w = t >> 6, l = t & 63;
    const int lr = l & 15, lh = l >> 4;
    const int row0 = blockIdx.x * 64;

    for (int i = t; i < K * 64; i += 256) {
        int k = i >> 6, r = i & 63;
        jl[i] = nmap[(size_t)(row0 + r) * K + k];
    }
    __syncthreads();

    const int rr0 = (w << 4) + (l >> 3);
    const int qq = (l & 7) ^ (l >> 3);

    auto stage = [&](int buf, int k) {
        const __hip_bfloat16* Wk = Wt + (size_t)k * 4096;
#pragma unroll
        for (int i = 0; i < 2; ++i) {
            int rr = rr0 + (i << 3);
            int j = jl[(k << 6) + rr];
            __builtin_amdgcn_global_load_lds(
                (const __attribute__((address_space(1))) void*)(feat + ((size_t)j << 6) + (qq << 3)),
                (__attribute__((address_space(3))) void*)(AbufS + buf * 4096 + (w << 10) + (i << 9)),
                16, 0, 0);
            __builtin_amdgcn_global_load_lds(
                (const __attribute__((address_space(1))) void*)(Wk + (rr << 6) + (qq << 3)),
                (__attribute__((address_space(3))) void*)(BbufS + buf * 4096 + (w << 10) + (i << 9)),
                16, 0, 0);
        }
    };

    auto stage_epi = [&](int buf) {
        short* dstW = BbufS + buf * 4096;
#pragma unroll
        for (int i = 0; i < 2; ++i) {
            int s = t + i * 256;
            int r = s >> 3, qp = s & 7;
            int q = qp ^ (r >> 4);
            __builtin_amdgcn_global_load_lds(
                (const __attribute__((address_space(1))) void*)(Woutg + (r << 5) + (q << 2)),
                (__attribute__((address_space(3))) void*)(dstW + (w << 9) + (i << 11)),
                16, 0, 0);
        }
        __builtin_amdgcn_global_load_lds(
            (const __attribute__((address_space(1))) void*)(Wgb + (t << 3)),
            (__attribute__((address_space(3))) void*)(WgL + (w << 9)),
            16, 0, 0);
        if (t < 40)
            __builtin_amdgcn_global_load_lds(
                (const __attribute__((address_space(1))) void*)(pack + (t << 2)),
                (__attribute__((address_space(3))) void*)packL,
                16, 0, 0);
    };

    f32x4 acc[4] = {};
    const int arow = (w << 4) + lr;

#define COMPUTE(cur_)                                                            \
    {                                                                            \
        const short* Ab = AbufS + (cur_) * 4096;                                 \
        const short* Bb = BbufS + (cur_) * 4096;                                 \
        _Pragma("unroll")                                                        \
        for (int kk = 0; kk < 2; ++kk) {                                         \
            int q = (kk << 2) + lh;                                              \
            short8 a = *(const short8*)&Ab[(arow << 6) + ((q ^ (arow & 7)) << 3)];\
            _Pragma("unroll")                                                    \
            for (int ct = 0; ct < 4; ++ct) {                                     \
                int dr = (ct << 4) + lr;                                         \
                short8 b = *(const short8*)&Bb[(dr << 6) + ((q ^ (dr & 7)) << 3)];\
                acc[ct] = __builtin_amdgcn_mfma_f32_16x16x32_bf16(a, b, acc[ct], 0, 0, 0); \
            }                                                                    \
        }                                                                        \
    }

    stage(0, 0);

    int cur = 0;
    for (int k = 0; k < K; ++k) {
        if (k + 1 < K) {
            stage(cur ^ 1, k + 1);
            asm volatile("s_waitcnt vmcnt(4)" ::: "memory");
        } else {
            stage_epi(cur ^ 1);
            asm volatile("s_waitcnt vmcnt(0)" ::: "memory");
        }
        asm volatile("s_barrier" ::: "memory");
        COMPUTE(cur)
        asm volatile("s_barrier" ::: "memory");
        cur ^= 1;
    }
#undef COMPUTE
    // epi weights now in BbufS[cur], WgL, packL

    short* tl = AbufS;                       // t-tile [64][72] bf16 (Abuf dead)
    float* WoutL = (float*)(BbufS + cur * 4096);

#pragma unroll
    for (int ct = 0; ct < 4; ++ct) {
        int col = (ct << 4) + lr;
        float bv = packL[col];
#pragma unroll
        for (int rr = 0; rr < 4; ++rr) {
            int rl = (w << 4) + (lh << 2) + rr;
            float v = fmaxf(acc[ct][rr] + bv, 0.f);
            tl[rl * 72 + col] = (short)fbf(v);
        }
    }
    __syncthreads();

    const int g4 = t & 3, rloc = t >> 2;
    const short* trow = tl + rloc * 72 + (g4 << 4);
    float tv[16];
    {
        short8 u0 = *(const short8*)trow;
        short8 u1 = *(const short8*)(trow + 8);
#pragma unroll
        for (int j = 0; j < 8; ++j) {
            tv[j]     = bfu((unsigned short)u0[j]);
            tv[8 + j] = bfu((unsigned short)u1[j]);
        }
    }
    float ph[32];
#pragma unroll
    for (int d = 0; d < 32; ++d) ph[d] = 0.f;
#pragma unroll
    for (int i = 0; i < 16; ++i) {
        float tc = tv[i];
        const float* wrow = WoutL + (((g4 << 4) + i) << 5);
#pragma unroll
        for (int q = 0; q < 8; ++q) {
            f32x4 wv = *(const f32x4*)&wrow[(q ^ g4) << 2];
            ph[q * 4 + 0] = fmaf(tc, wv[0], ph[q * 4 + 0]);
            ph[q * 4 + 1] = fmaf(tc, wv[1], ph[q * 4 + 1]);
            ph[q * 4 + 2] = fmaf(tc, wv[2], ph[q * 4 + 2]);
            ph[q * 4 + 3] = fmaf(tc, wv[3], ph[q * 4 + 3]);
        }
    }
#pragma unroll
    for (int m = 1; m < 4; m <<= 1) {
#pragma unroll
        for (int d = 0; d < 32; ++d) ph[d] += __shfl_xor(ph[d], m);
    }
#pragma unroll
    for (int d = 0; d < 32; ++d) ph[d] += packL[64 + d];

    {
        float* ho = hx_out + ((size_t)(row0 + rloc) << 5);
#pragma unroll
        for (int G = 0; G < 4; ++G)
            if (g4 == G) {
                float4 v0 = {ph[G * 8 + 0], ph[G * 8 + 1], ph[G * 8 + 2], ph[G * 8 + 3]};
                float4 v1 = {ph[G * 8 + 4], ph[G * 8 + 5], ph[G * 8 + 6], ph[G * 8 + 7]};
                ((float4*)ho)[G * 2 + 0] = v0;
                ((float4*)ho)[G * 2 + 1] = v1;
            }
    }

    float ga[16];
#pragma unroll
    for (int j = 0; j < 16; ++j) ga[j] = packL[96 + (g4 << 4) + j];
#pragma unroll
    for (int d = 0; d < 32; ++d) {
        float hd = ph[d];
        const short* wg = WgL + (d << 6) + (g4 << 4);
        short8 w0 = *(const short8*)wg;
        short8 w1 = *(const short8*)(wg + 8);
#pragma unroll
        for (int j = 0; j < 8; ++j) {
            ga[j]     = fmaf(hd, bfu((unsigned short)w0[j]), ga[j]);
            ga[8 + j] = fmaf(hd, bfu((unsigned short)w1[j]), ga[8 + j]);
        }
    }
    {
        short8 o0, o1;
#pragma unroll
        for (int j = 0; j < 8; ++j) {
            float g0 = 1.f / (1.f + __expf(-ga[j]));
            float g1 = 1.f / (1.f + __expf(-ga[8 + j]));
            o0[j] = (short)fbf(g0 * tv[j]);
            o1[j] = (short)fbf(g1 * tv[8 + j]);
        }
        short* go = (short*)gout + ((size_t)(row0 + rloc) << 6) + (g4 << 4);
        *(short8*)go = o0;
        *(short8*)(go + 8) = o1;
    }
}

// ---------------------------------------------------------------------------
// reduce_relu_bf (r10-proven): out_bf16 = relu(sum_ch chunk + bias[c])
// ---------------------------------------------------------------------------
__global__ void reduce_relu_bf(const float* __restrict__ in, const float* __restrict__ bias,
                               __hip_bfloat16* __restrict__ outb, int nv, int ch)
{
    int i = blockIdx.x * blockDim.x + threadIdx.x;
    if (i >= nv) return;
    const float4* in4 = (const float4*)in;
    float4 s = in4[i];
    for (int c = 1; c < ch; ++c) {
        float4 v = in4[(size_t)c * nv + i];
        s.x += v.x; s.y += v.y; s.z += v.z; s.w += v.w;
    }
    int cb = (i << 2) & 63;
    ushort4 o;
    o.x = fbf(fmaxf(s.x + bias[cb + 0], 0.f));
    o.y = fbf(fmaxf(s.y + bias[cb + 1], 0.f));
    o.z = fbf(fmaxf(s.z + bias[cb + 2], 0.f));
    o.w = fbf(fmaxf(s.w + bias[cb + 3], 0.f));
    ((ushort4*)outb)[i] = o;
}

// ---------------------------------------------------------------------------
// epi_full (r10-proven, 8 lanes/row). smode 0: bf16 +bias+relu; 2: f32 raw.
// ---------------------------------------------------------------------------
__global__ __launch_bounds__(256) void epi_full(
    const void* __restrict__ srcp, int smode, int ch, const float* __restrict__ bconv,
    const float* __restrict__ Wout, const float* __restrict__ bout,
    const float* __restrict__ Wg, const float* __restrict__ bg,
    float* __restrict__ hx_out, __hip_bfloat16* __restrict__ gout, int N)
{
    __shared__ float Woutl[64 * 32];
    __shared__ float Wgl[32 * 64];
    __shared__ float boutl[32];
    __shared__ float bgl[64];
    __shared__ float bcl[64];

    const int t = threadIdx.x;
    for (int i = t; i < 2048; i += 256) {
        int r = i >> 5, col = i & 31;
        int q = col >> 2, e = col & 3;
        Woutl[(r << 5) + ((q ^ (r >> 3)) << 2) + e] = Wout[i];
        Wgl[i] = Wg[i];
    }
    if (t < 32) boutl[t] = bout[t];
    if (t >= 64 && t < 128) bgl[t - 64] = bg[t - 64];
    if (t >= 128 && t < 192) bcl[t - 128] = bconv ? bconv[t - 128] : 0.f;
    __syncthreads();

    const int g = t & 7;
    const int row = blockIdx.x * 32 + (t >> 3);
    const int c0 = g << 3;

    float tv[8];
    if (smode == 0) {
        const ushort4* sb = (const ushort4*)((const __hip_bfloat16*)srcp + ((size_t)row << 6) + c0);
        ushort4 v0 = sb[0], v1 = sb[1];
        tv[0] = bfu(v0.x); tv[1] = bfu(v0.y); tv[2] = bfu(v0.z); tv[3] = bfu(v0.w);
        tv[4] = bfu(v1.x); tv[5] = bfu(v1.y); tv[6] = bfu(v1.z); tv[7] = bfu(v1.w);
    } else {
        const float4* sf = (const float4*)((const float*)srcp + ((size_t)row << 6) + c0);
        float4 a = sf[0], b = sf[1];
        tv[0] = a.x; tv[1] = a.y; tv[2] = a.z; tv[3] = a.w;
        tv[4] = b.x; tv[5] = b.y; tv[6] = b.z; tv[7] = b.w;
    }
    if (smode != 2) {
#pragma unroll
        for (int i = 0; i < 8; ++i) tv[i] = fmaxf(tv[i] + bcl[c0 + i], 0.f);
    }

    float ph[32];
#pragma unroll
    for (int d = 0; d < 32; ++d) ph[d] = 0.f;
#pragma unroll
    for (int i = 0; i < 8; ++i) {
        float tc = tv[i];
        const float* wr = &Woutl[(c0 + i) << 5];
#pragma unroll
        for (int q = 0; q < 8; ++q) {
            f32x4 wv = *(const f32x4*)&wr[(q ^ g) << 2];
            ph[q * 4 + 0] = fmaf(tc, wv[0], ph[q * 4 + 0]);
            ph[q * 4 + 1] = fmaf(tc, wv[1], ph[q * 4 + 1]);
            ph[q * 4 + 2] = fmaf(tc, wv[2], ph[q * 4 + 2]);
            ph[q * 4 + 3] = fmaf(tc, wv[3], ph[q * 4 + 3]);
        }
    }
#pragma unroll
    for (int m = 1; m < 8; m <<= 1) {
#pragma unroll
        for (int d = 0; d < 32; ++d) ph[d] += __shfl_xor(ph[d], m);
    }
#pragma unroll
    for (int d = 0; d < 32; ++d) ph[d] += boutl[d];

    {
        float* ho = hx_out + ((size_t)row << 5);
#pragma unroll
        for (int G = 0; G < 8; ++G)
            if (g == G) {
                float4 v = {ph[G * 4 + 0], ph[G * 4 + 1], ph[G * 4 + 2], ph[G * 4 + 3]};
                ((float4*)ho)[G] = v;
            }
    }

    float ga[8];
#pragma unroll
    for (int j = 0; j < 8; ++j) ga[j] = bgl[c0 + j];
#pragma unroll
    for (int d = 0; d < 32; ++d) {
        float hd = ph[d];
        const float* wr = &Wgl[(d << 6) + c0];
        f32x4 w0 = *(const f32x4*)&wr[0];
        f32x4 w1 = *(const f32x4*)&wr[4];
        ga[0] = fmaf(hd, w0[0], ga[0]); ga[1] = fmaf(hd, w0[1], ga[1]);
        ga[2] = fmaf(hd, w0[2], ga[2]); ga[3] = fmaf(hd, w0[3], ga[3]);
        ga[4] = fmaf(hd, w1[0], ga[4]); ga[5] = fmaf(hd, w1[1], ga[5]);
        ga[6] = fmaf(hd, w1[2], ga[6]); ga[7] = fmaf(hd, w1[3], ga[7]);
    }
    {
        unsigned short ob[8];
#pragma unroll
        for (int j = 0; j < 8; ++j) {
            float gg = 1.f / (1.f + __expf(-ga[j]));
            ob[j] = fbf(gg * tv[j]);
        }
        ushort4* go = (ushort4*)(gout + ((size_t)row << 6) + c0);
        ushort4 o0 = {ob[0], ob[1], ob[2], ob[3]};
        ushort4 o1 = {ob[4], ob[5], ob[6], ob[7]};
        go[0] = o0; go[1] = o1;
    }
}

// ---------------------------------------------------------------------------
extern "C" void kernel_launch(void* const* d_in, const int* in_sizes, int n_in,
                              void* d_out, int out_size, void* d_ws, size_t ws_size,
                              hipStream_t stream)
{
    const float* x    = (const float*)d_in[0];
    const float* Wg0  = (const float*)d_in[1];
    const float* bg0  = (const float*)d_in[2];
    const float* Wg1  = (const float*)d_in[3];
    const float* bg1  = (const float*)d_in[4];
    const float* Wout = (const float*)d_in[5];
    const float* bout = (const float*)d_in[6];
    const float* WA   = (const float*)d_in[7];
    const float* bA   = (const float*)d_in[8];
    const float* WB   = (const float*)d_in[9];
    const float* bB   = (const float*)d_in[10];
    const float* WD   = (const float*)d_in[11];
    const float* bD   = (const float*)d_in[12];
    const float* WC   = (const float*)d_in[13];
    const float* bC   = (const float*)d_in[14];
    const int* nmap[4] = {(const int*)d_in[15], (const int*)d_in[16],
                          (const int*)d_in[17], (const int*)d_in[18]};
    const int* ndm[3]  = {(const int*)d_in[19], (const int*)d_in[20],
                          (const int*)d_in[21]};

    float* out = (float*)d_out;
    __hip_bfloat16* featbf0 = (__hip_bfloat16*)d_ws;
    __hip_bfloat16* featbf1 = featbf0 + (size_t)N0 * 64;
    __hip_bfloat16* convbf  = featbf1 + (size_t)N0 * 64;
    float* conv32 = (float*)(convbf + (size_t)N0 * 64);   // up to 8 chunks of N2*64 f32
    __hip_bfloat16* WAt = (__hip_bfloat16*)(conv32 + (size_t)N2 * 64 * 8);
    __hip_bfloat16* WBt = WAt + 27 * 4096;
    __hip_bfloat16* WCt = WBt + 27 * 4096;
    __hip_bfloat16* WDt = WCt + 27 * 4096;
    __hip_bfloat16* Wgb = WDt + 8 * 4096;         // [0]=bf16(Wg1), [1]=bf16(Wg0)
    float* packw = (float*)(Wgb + 4096);          // pack0 (160) | pack1 (160)

    const int Ns[4] = {N0, N1, N2, N3};
    size_t off[7];
    off[0] = 0;
    off[1] = off[0] + (size_t)N0 * 32;
    off[2] = off[1] + (size_t)N0 * 32;
    off[3] = off[2] + (size_t)N1 * 32;
    off[4] = off[3] + (size_t)N1 * 32;
    off[5] = off[4] + (size_t)N2 * 32;
    off[6] = off[5] + (size_t)N2 * 32;

    hipLaunchKernelGGL(prep_all, dim3((89 * 4096 + 4416 + 255) / 256), dim3(256), 0, stream,
                       WA, WB, WC, WD, Wg0, Wg1, bB, bC, bout, bg0, bg1,
                       WAt, Wgb, packw);

    // r10 chunk policy for plain convs at small scales
    auto chunks = [&](int Nout, int K) -> int {
        if (Nout >= 16384) return 1;
        if (Nout == 4096) return (K == 27) ? 4 : 2;
        return (K == 27) ? 7 : 4;   // N3
    };
    // plain conv (A/D): returns ch if f32 chunk partials in conv32, else 0
    auto convAD = [&](const __hip_bfloat16* fin, const int* nm,
                      const __hip_bfloat16* Wt, int Nout, int K,
                      const float* bias2, __hip_bfloat16* dst) -> int {
        int ch = chunks(Nout, K);
        if (ch > 1) {
            hipLaunchKernelGGL(spconv_mfma, dim3(Nout / 64, ch), dim3(256), 0, stream,
                               fin, nm, Wt, (void*)conv32, (const float*)nullptr,
                               Nout, K, 1);
            return ch;
        }
        hipLaunchKernelGGL(spconv_mfma, dim3(Nout / 64, 1), dim3(256), 0, stream,
                           fin, nm, Wt, (void*)dst, bias2, Nout, K, 2);
        return 0;
    };

    // init: hx0 -> out0 ; featbf0 = bf16(sigmoid(hx0@Wg0+bg0) * x)
    hipLaunchKernelGGL(epi_full, dim3(N0 / 32), dim3(256), 0, stream,
                       (const void*)x, 2, 1, (const float*)nullptr, Wout, bout, Wg0, bg0,
                       out + off[0], featbf0, N0);

    for (int s = 0; s < 3; ++s) {
        int N = Ns[s], Nn = Ns[s + 1];

        // ---- conv A (bias+relu) -> featbf1 ----
        int mA = convAD(featbf0, nmap[s], WAt, N, 27, bA, featbf1);
        if (mA)
            hipLaunchKernelGGL(reduce_relu_bf, dim3((N * 16 + 255) / 256), dim3(256), 0, stream,
                               conv32, bA, featbf1, N * 16, mA);

        // ---- conv B: fused at N<=16384, unfused at N0 ----
        if (N >= 65536) {
            hipLaunchKernelGGL(spconv_mfma, dim3(N / 64, 1), dim3(256), 0, stream,
                               featbf1, nmap[s], WBt, (void*)convbf,
                               (const float*)nullptr, N, 27, 0);
            hipLaunchKernelGGL(epi_full, dim3(N / 32), dim3(256), 0, stream,
                               (const void*)convbf, 0, 1, bB, Wout, bout, Wg1, bg1,
                               out + off[s * 2 + 1], featbf0, N);
        } else {
            hipLaunchKernelGGL(spconv_fused, dim3(N / 64), dim3(256), 0, stream,
                               featbf1, nmap[s], WBt, 27,
                               Wout, Wgb, packw, out + off[s * 2 + 1], featbf0);
        }

        // ---- conv D (downsample, bias+relu) -> featbf1 ----
        int mD = convAD(featbf0, ndm[s], WDt, Nn, 8, bD, featbf1);
        if (mD)
            hipLaunchKernelGGL(reduce_relu_bf, dim3((Nn * 16 + 255) / 256), dim3(256), 0, stream,
                               conv32, bD, featbf1, Nn * 16, mD);

        // ---- conv C: always N<=16384 -> fused ----
        hipLaunchKernelGGL(spconv_fused, dim3(Nn / 64), dim3(256), 0, stream,
                           featbf1, nmap[s + 1], WCt, 27,
                           Wout, Wgb + 2048, packw + 160, out + off[s * 2 + 2], featbf0);
    }
}